// Round 1
// baseline (274.498 us; speedup 1.0000x reference)
//
#include <hip/hip_runtime.h>
#include <cstdint>
#include <cstddef>

#define B_   512
#define V_   6890
#define VP   6912      // padded vertex count (multiple of 128)
#define NJ   24
#define KF   224       // padded feature length: 207 pose + 10 betas + 1 + 6 pad
#define NP   46

// ---- constants: per-DOF axes (pre-normalized, from JOINT_AXES incl. _pin values), ridx, parents ----
__constant__ float c_axes[47][3] = {
  { 0.f, 0.f, 1.f}, { 1.f, 0.f, 0.f}, { 0.f, 1.f, 0.f},          // J0
  { 0.f, 0.f, 1.f}, { 1.f, 0.f, 0.f}, { 0.f, 1.f, 0.f},          // J1
  { 0.f, 0.f,-1.f},                                              // J2
  {-0.10501402f,-0.17402183f, 0.97912636f},                      // J3 pin
  { 0.78718019f, 0.60474702f,-0.12094817f},                      // J4 pin
  { 0.58095459f, 0.00000217f,-0.81393598f},                      // J5 pin
  { 0.f, 0.f, 1.f}, {-1.f, 0.f, 0.f}, { 0.f,-1.f, 0.f},          // J6
  { 0.f, 0.f,-1.f},                                              // J7
  {-0.10501402f,-0.17402183f, 0.97912636f},                      // J8 pin
  {-0.78718019f,-0.60474702f,-0.12094817f},                      // J9 pin
  {-0.58095459f, 0.00000217f,-0.81393598f},                      // J10 pin
  { 1.f, 0.f, 0.f}, { 0.f, 0.f, 1.f}, { 0.f, 1.f, 0.f},          // J11
  { 1.f, 0.f, 0.f}, { 0.f, 0.f, 1.f}, { 0.f, 1.f, 0.f},          // J12
  { 1.f, 0.f, 0.f}, { 0.f, 0.f, 1.f}, { 0.f, 1.f, 0.f},          // J13
  { 0.f, 1.f, 0.f}, { 0.f, 0.f,-1.f}, {-1.f, 0.f, 0.f},          // J14
  { 1.f, 0.f, 0.f}, { 0.f, 1.f, 0.f}, { 0.f, 0.f, 1.f},          // J15
  { 0.0494f, 0.0366f, 0.99810825f},                              // J16
  {-0.01716099f, 0.99266564f,-0.11966796f},                      // J17
  { 1.f, 0.f, 0.f}, { 0.f, 0.f,-1.f},                            // J18
  { 0.f, 1.f, 0.f}, { 0.f, 0.f, 1.f}, { 1.f, 0.f, 0.f},          // J19
  { 1.f, 0.f, 0.f}, { 0.f, 1.f, 0.f}, { 0.f, 0.f, 1.f},          // J20
  {-0.0494f,-0.0366f, 0.99810825f},                              // J21
  { 0.01716099f,-0.99266564f,-0.11966796f},                      // J22
  {-1.f, 0.f, 0.f}, { 0.f, 0.f,-1.f},                            // J23
  { 0.f, 0.f, 0.f}                                               // 46: identity pad
};
__constant__ int c_ridx[24][3] = {
  {0,1,2},{3,4,5},{6,46,46},{7,46,46},{8,46,46},{9,46,46},
  {10,11,12},{13,46,46},{14,46,46},{15,46,46},{16,46,46},
  {17,18,19},{20,21,22},{23,24,25},{26,27,28},{29,30,31},
  {32,46,46},{33,46,46},{34,35,46},{36,37,38},{39,40,41},
  {42,46,46},{43,46,46},{44,45,46}
};
__constant__ int c_par[24] = {-1,0,1,2,3,4,0,6,7,8,9,0,11,12,12,14,15,16,17,12,19,20,21,22};

__device__ __forceinline__ void mm3(const float* A, const float* Bm, float* C) {
#pragma unroll
  for (int i = 0; i < 3; ++i)
#pragma unroll
    for (int j = 0; j < 3; ++j)
      C[i*3+j] = A[i*3+0]*Bm[0+j] + A[i*3+1]*Bm[3+j] + A[i*3+2]*Bm[6+j];
}
__device__ __forceinline__ void mm3_bt(const float* A, const float* Bm, float* C) {
#pragma unroll
  for (int i = 0; i < 3; ++i)
#pragma unroll
    for (int j = 0; j < 3; ++j)
      C[i*3+j] = A[i*3+0]*Bm[j*3+0] + A[i*3+1]*Bm[j*3+1] + A[i*3+2]*Bm[j*3+2];
}

// ---- K0: build transposed/padded PD: pdt[c][k][v] = [posedirs | shapedirs | v_template | 0] ----
__global__ void k0_pdt(const float* __restrict__ posed, const float* __restrict__ sd,
                       const float* __restrict__ vt, float* __restrict__ pdt) {
  int i = blockIdx.x * 256 + threadIdx.x;        // 0 .. 3*KF*VP-1 (exact grid)
  int v = i % VP;
  int r = i / VP;          // 0..671
  int c = r / KF;
  int k = r % KF;
  float val = 0.f;
  if (v < V_) {
    if (k < 207)       val = posed[(v*3 + c)*207 + k];
    else if (k < 217)  val = sd[(v*3 + c)*10 + (k - 207)];
    else if (k == 217) val = vt[v*3 + c];
  }
  pdt[i] = val;
}

// ---- K1: jts[j][c][0] = Jreg@v_template ; jts[j][c][1+kb] = Jreg@shapedirs ----
__global__ void k1_jts(const float* __restrict__ jreg, const float* __restrict__ vt,
                       const float* __restrict__ sd, float* __restrict__ jts) {
  const int j = blockIdx.x / 3, c = blockIdx.x % 3;
  float acc[11];
#pragma unroll
  for (int i = 0; i < 11; ++i) acc[i] = 0.f;
  for (int v = threadIdx.x; v < V_; v += 256) {
    float w = jreg[j*V_ + v];
    acc[0] += w * vt[v*3 + c];
    const float* s = sd + (v*3 + c)*10;
#pragma unroll
    for (int k = 0; k < 10; ++k) acc[1+k] += w * s[k];
  }
#pragma unroll
  for (int i = 0; i < 11; ++i)
    for (int o = 32; o > 0; o >>= 1) acc[i] += __shfl_xor(acc[i], o, 64);
  __shared__ float red[4][11];
  int wid = threadIdx.x >> 6, ln = threadIdx.x & 63;
  if (ln == 0) {
#pragma unroll
    for (int i = 0; i < 11; ++i) red[wid][i] = acc[i];
  }
  __syncthreads();
  if (threadIdx.x == 0) {
#pragma unroll
    for (int i = 0; i < 11; ++i)
      jts[(j*3 + c)*11 + i] = red[0][i] + red[1][i] + red[2][i] + red[3][i];
  }
}

// ---- K2: per-batch pose math -> F[b][224], M[b][24][12] ----
__global__ void k2_pose(const float* __restrict__ poses, const float* __restrict__ betas,
                        const float* __restrict__ trans, const float* __restrict__ apose,
                        const float* __restrict__ pjr, const float* __restrict__ jts,
                        float* __restrict__ Fw, float* __restrict__ Mw) {
  const int b = blockIdx.x;
  const int t = threadIdx.x;
  __shared__ float Rd[47][9];
  __shared__ float Rj[24][9];
  __shared__ float Rl[24][9];
  __shared__ float jl[24][3];
  __shared__ float G[24][12];   // [0..8]=R rowmajor, [9..11]=t

  if (t < 47) {
    float q  = (t < NP) ? poses[b*NP + t] : 0.f;
    float ax = c_axes[t][0], ay = c_axes[t][1], az = c_axes[t][2];
    float s = sinf(q), cq = cosf(q);
    float u = 1.f - cq;
    Rd[t][0] = u*ax*ax + cq;   Rd[t][1] = u*ax*ay - s*az; Rd[t][2] = u*ax*az + s*ay;
    Rd[t][3] = u*ax*ay + s*az; Rd[t][4] = u*ay*ay + cq;   Rd[t][5] = u*ay*az - s*ax;
    Rd[t][6] = u*ax*az - s*ay; Rd[t][7] = u*ay*az + s*ax; Rd[t][8] = u*az*az + cq;
  }
  if (t < NJ) {
    const float* jr = jts + t*33;
#pragma unroll
    for (int c = 0; c < 3; ++c) {
      float a = jr[c*11];
#pragma unroll
      for (int k = 0; k < 10; ++k) a += jr[c*11 + 1 + k] * betas[b*10 + k];
      jl[t][c] = a;
    }
  }
  __syncthreads();
  if (t < NJ) {
    float C1[9], C2[9];
    const int r0 = c_ridx[t][0], r1 = c_ridx[t][1], r2 = c_ridx[t][2];
    mm3(&Rd[r0][0], &Rd[r1][0], C1);
    mm3(C1, &Rd[r2][0], C2);                 // Rj
#pragma unroll
    for (int e = 0; e < 9; ++e) Rj[t][e] = C2[e];
    float P[9], Ap[9];
#pragma unroll
    for (int e = 0; e < 9; ++e) { P[e] = pjr[t*9 + e]; Ap[e] = apose[t*9 + e]; }
    mm3(P, C2, C1);                          // P @ Rj
    mm3_bt(C1, P, C2);                       // @ P^T
    mm3(Ap, C2, C1);                         // apose @ ...
#pragma unroll
    for (int e = 0; e < 9; ++e) Rl[t][e] = C1[e];
  }
  __syncthreads();
  if (t == 0) {                              // FK (serial, tiny)
#pragma unroll
    for (int e = 0; e < 9; ++e) G[0][e] = Rl[0][e];
    G[0][9] = jl[0][0]; G[0][10] = jl[0][1]; G[0][11] = jl[0][2];
    for (int j = 1; j < NJ; ++j) {
      int p = c_par[j];
      float R[9];
      mm3(&G[p][0], &Rl[j][0], R);
#pragma unroll
      for (int e = 0; e < 9; ++e) G[j][e] = R[e];
      float d0 = jl[j][0]-jl[p][0], d1 = jl[j][1]-jl[p][1], d2 = jl[j][2]-jl[p][2];
      G[j][9]  = G[p][9]  + G[p][0]*d0 + G[p][1]*d1 + G[p][2]*d2;
      G[j][10] = G[p][10] + G[p][3]*d0 + G[p][4]*d1 + G[p][5]*d2;
      G[j][11] = G[p][11] + G[p][6]*d0 + G[p][7]*d1 + G[p][8]*d2;
    }
  }
  __syncthreads();
  if (t < NJ) {
    float tx = trans[b*3+0], ty = trans[b*3+1], tz = trans[b*3+2];
    float a0 = G[t][9]  - (G[t][0]*jl[t][0] + G[t][1]*jl[t][1] + G[t][2]*jl[t][2]) + tx;
    float a1 = G[t][10] - (G[t][3]*jl[t][0] + G[t][4]*jl[t][1] + G[t][5]*jl[t][2]) + ty;
    float a2 = G[t][11] - (G[t][6]*jl[t][0] + G[t][7]*jl[t][1] + G[t][8]*jl[t][2]) + tz;
    float* m = Mw + b*288 + t*12;
#pragma unroll
    for (int e = 0; e < 9; ++e) m[e] = G[t][e];
    m[9] = a0; m[10] = a1; m[11] = a2;
  }
  for (int k = t; k < KF; k += 64) {         // F row: [pose_feat | betas | 1 | 0pad]
    float val;
    if (k < 207) {
      int jj = k / 9 + 1;
      int e  = k % 9;
      val = Rj[jj][e] - ((e == 0 || e == 4 || e == 8) ? 1.f : 0.f);
    } else if (k < 217) val = betas[b*10 + (k - 207)];
    else if (k == 217)  val = 1.f;
    else                val = 0.f;
    Fw[b*KF + k] = val;
  }
}

// ---- K3: fused v_posed GEMM + skinning. block: 128 v x 16 b; thread: 4 v x 2 b ----
__global__ __launch_bounds__(256) void k3_verts(
    const float* __restrict__ pdt,   // [3][KF][VP]
    const float* __restrict__ Fw,    // [B][KF]
    const float* __restrict__ Mw,    // [B][24][12]
    const float* __restrict__ sw,    // [V][24]
    float* __restrict__ out)         // [B][V][3]
{
  __shared__ float Fl[16*KF];
  __shared__ float Ml[16*288];
  const int bt = blockIdx.x & 31;    // b-tile fast -> consecutive blocks share PD v-tile (L2)
  const int vt = blockIdx.x >> 5;
  const int b0 = bt * 16;
  const int t  = threadIdx.x;

  const float* Fs = Fw + b0*KF;
  for (int i = t; i < 16*KF; i += 256) Fl[i] = Fs[i];
  const float* Ms = Mw + b0*288;
  for (int i = t; i < 16*288; i += 256) Ml[i] = Ms[i];
  __syncthreads();

  const int lane = t & 31;
  const int bq   = t >> 5;                  // 0..7
  const int vb   = vt*128 + lane*4;         // 4 consecutive vertices
  const int bb0  = bq*2, bb1 = bq*2 + 1;

  float acc[2][4][3];
#pragma unroll
  for (int x = 0; x < 2; ++x)
#pragma unroll
    for (int y = 0; y < 4; ++y)
#pragma unroll
      for (int z = 0; z < 3; ++z) acc[x][y][z] = 0.f;

  const float* fl0 = Fl + bb0*KF;
  const float* fl1 = Fl + bb1*KF;
  const float* pb  = pdt + vb;

#pragma unroll 2
  for (int k = 0; k < KF; k += 4) {
    float4 f0 = *(const float4*)(fl0 + k);
    float4 f1 = *(const float4*)(fl1 + k);
#pragma unroll
    for (int kk = 0; kk < 4; ++kk) {
      float s0 = (&f0.x)[kk];
      float s1 = (&f1.x)[kk];
#pragma unroll
      for (int c = 0; c < 3; ++c) {
        const float4 p = *(const float4*)(pb + (size_t)(c*KF + k + kk)*VP);
        acc[0][0][c] += p.x*s0; acc[0][1][c] += p.y*s0; acc[0][2][c] += p.z*s0; acc[0][3][c] += p.w*s0;
        acc[1][0][c] += p.x*s1; acc[1][1][c] += p.y*s1; acc[1][2][c] += p.z*s1; acc[1][3][c] += p.w*s1;
      }
    }
  }

  // skinning: vo += s_vj * (R_j @ vp + t_j); joint data read once per thread, reused by 8 pairs
  float vo[2][4][3];
#pragma unroll
  for (int x = 0; x < 2; ++x)
#pragma unroll
    for (int y = 0; y < 4; ++y)
#pragma unroll
      for (int z = 0; z < 3; ++z) vo[x][y][z] = 0.f;

#pragma unroll 1
  for (int j = 0; j < NJ; ++j) {
    const float4* m0p = (const float4*)(Ml + bb0*288 + j*12);
    float4 a0 = m0p[0], b0v = m0p[1], c0 = m0p[2];
    const float4* m1p = (const float4*)(Ml + bb1*288 + j*12);
    float4 a1 = m1p[0], b1v = m1p[1], c1 = m1p[2];
#pragma unroll
    for (int vi = 0; vi < 4; ++vi) {
      int vv = vb + vi;
      int vc = (vv < V_) ? vv : (V_ - 1);
      float s = sw[vc*24 + j];
      {
        float x = acc[0][vi][0], y = acc[0][vi][1], z = acc[0][vi][2];
        vo[0][vi][0] += s * (a0.x*x + a0.y*y + a0.z*z + c0.y);
        vo[0][vi][1] += s * (a0.w*x + b0v.x*y + b0v.y*z + c0.z);
        vo[0][vi][2] += s * (b0v.z*x + b0v.w*y + c0.x*z + c0.w);
      }
      {
        float x = acc[1][vi][0], y = acc[1][vi][1], z = acc[1][vi][2];
        vo[1][vi][0] += s * (a1.x*x + a1.y*y + a1.z*z + c1.y);
        vo[1][vi][1] += s * (a1.w*x + b1v.x*y + b1v.y*z + c1.z);
        vo[1][vi][2] += s * (b1v.z*x + b1v.w*y + c1.x*z + c1.w);
      }
    }
  }

#pragma unroll
  for (int vi = 0; vi < 4; ++vi) {
    int vv = vb + vi;
    if (vv < V_) {
      float* o0 = out + ((size_t)(b0 + bb0)*V_ + vv)*3;
      o0[0] = vo[0][vi][0]; o0[1] = vo[0][vi][1]; o0[2] = vo[0][vi][2];
      float* o1 = out + ((size_t)(b0 + bb1)*V_ + vv)*3;
      o1[0] = vo[1][vi][0]; o1[1] = vo[1][vi][1]; o1[2] = vo[1][vi][2];
    }
  }
}

extern "C" void kernel_launch(void* const* d_in, const int* in_sizes, int n_in,
                              void* d_out, int out_size, void* d_ws, size_t ws_size,
                              hipStream_t stream) {
  (void)in_sizes; (void)n_in; (void)out_size; (void)ws_size;
  const float* betas      = (const float*)d_in[0];
  const float* poses      = (const float*)d_in[1];
  const float* trans      = (const float*)d_in[2];
  const float* v_template = (const float*)d_in[3];
  const float* shapedirs  = (const float*)d_in[4];
  const float* posedirs   = (const float*)d_in[5];
  const float* jreg       = (const float*)d_in[6];
  const float* skinw      = (const float*)d_in[7];
  const float* apose      = (const float*)d_in[8];
  const float* pjr        = (const float*)d_in[9];
  float* out = (float*)d_out;
  float* ws  = (float*)d_ws;

  float* pdt = ws;                       // 3*KF*VP        = 4,644,864 floats
  float* Fw  = ws + 4644864;             // B*KF           =   114,688
  float* Mw  = ws + 4759552;             // B*24*12        =   147,456
  float* jts = ws + 4907008;             // 24*3*11        =       792

  hipLaunchKernelGGL(k0_pdt, dim3((3*KF*VP)/256), dim3(256), 0, stream,
                     posedirs, shapedirs, v_template, pdt);
  hipLaunchKernelGGL(k1_jts, dim3(72), dim3(256), 0, stream,
                     jreg, v_template, shapedirs, jts);
  hipLaunchKernelGGL(k2_pose, dim3(B_), dim3(64), 0, stream,
                     poses, betas, trans, apose, pjr, jts, Fw, Mw);
  hipLaunchKernelGGL(k3_verts, dim3(32 * (VP/128)), dim3(256), 0, stream,
                     pdt, Fw, Mw, skinw, out);
}